// Round 7
// baseline (781.554 us; speedup 1.0000x reference)
//
#include <hip/hip_runtime.h>
#include <stdint.h>

// N=16, M=4, D=32, K=256, H=64, W=64 ; P = 262144 pixels
// outputs (concat, read back as f32): sample (P*256), code (P, as float), logit (P*256)

#define TINY_F 1.17549435082228750797e-38f
#define LN2F   0.69314718055994530942f

// XLA:CPU vectorized log (GenerateVF32Log / Eigen plog), UNFUSED mul+add.
// Bit-exactness validated round 2 (code absmax == 0). DO NOT TOUCH.
__device__ __forceinline__ float plog_xla(float xin) {
  #pragma clang fp contract(off)
  uint32_t ix = __float_as_uint(xin);
  int e_i = (int)(ix >> 23) - 126;
  float x = __uint_as_float((ix & 0x007FFFFFu) | 0x3F000000u);
  float e = (float)e_i;
  bool lt = x < 0.707106781186547524f;
  float tmp = lt ? x : 0.0f;
  x = x - 1.0f;
  e = e - (lt ? 1.0f : 0.0f);
  x = x + tmp;
  float z  = x * x;
  float x3 = z * x;
  float y  =  7.0376836292e-2f * x + (-1.1514610310e-1f);
  float y1 = -1.2420140846e-1f * x +   1.4249322787e-1f;
  float y2 =  2.0000714765e-1f * x + (-2.4999993993e-1f);
  y  = y  * x +   1.1676998740e-1f;
  y1 = y1 * x + (-1.6668057665e-1f);
  y2 = y2 * x +   3.3333331174e-1f;
  y  = y * x3 + y1;
  y  = y * x3 + y2;
  y  = y * x3;
  y  = y + e * (-2.12194440e-4f);
  x  = x - 0.5f * z;
  x  = x + y;
  x  = x + e * 0.693359375f;
  return x;
}

// UNFUSED ascending square-sum (XLA reduce order). Pragma at body start.
__device__ __forceinline__ float sumsq_unfused(const float* v) {
  #pragma clang fp contract(off)
  float a = 0.0f;
  #pragma unroll
  for (int d = 0; d < 32; d++) a = a + v[d] * v[d];
  return a;
}

__device__ __forceinline__ void threefry2x32(uint32_t k0, uint32_t k1,
                                             uint32_t x0, uint32_t x1,
                                             uint32_t& o0, uint32_t& o1) {
  uint32_t ks2 = k0 ^ k1 ^ 0x1BD11BDAu;
  x0 += k0; x1 += k1;
#define TF_RND(r) { x0 += x1; x1 = (x1 << (r)) | (x1 >> (32 - (r))); x1 ^= x0; }
  TF_RND(13) TF_RND(15) TF_RND(26) TF_RND(6)
  x0 += k1; x1 += ks2 + 1u;
  TF_RND(17) TF_RND(29) TF_RND(16) TF_RND(24)
  x0 += ks2; x1 += k0 + 2u;
  TF_RND(13) TF_RND(15) TF_RND(26) TF_RND(6)
  x0 += k0; x1 += k1 + 3u;
  TF_RND(17) TF_RND(29) TF_RND(16) TF_RND(24)
  x0 += k1; x1 += ks2 + 4u;
  TF_RND(13) TF_RND(15) TF_RND(26) TF_RND(6)
  x0 += ks2; x1 += k0 + 5u;
#undef TF_RND
  o0 = x0; o1 = x1;
}

// EXACT gumbel (validated R2) — slow path + margin-certification only.
__device__ __forceinline__ float gumbel_from_bits(uint32_t bits) {
  uint32_t mant = bits >> 9;
  float f = __uint_as_float(0x3F800000u | mant) - 1.0f;
  float u = mant ? f : TINY_F;
  float t = -plog_xla(u);
  return -plog_xla(t);
}

// FAST gumbel via v_log_f32 (1-ulp log2). |g_fast - g_exact| <~ 5e-5.
__device__ __forceinline__ float gumbel_fast(uint32_t bits) {
  uint32_t mant = bits >> 9;
  float f = __uint_as_float(0x3F800000u | mant) - 1.0f;
  float u = mant ? f : TINY_F;
  float t = -(__log2f(u) * LN2F);
  return -(__log2f(t) * LN2F);
}

constexpr int KK = 256;
constexpr int DD = 32;
#define MARGIN 2.0e-4f

__global__ __launch_bounds__(256, 4)
void mcq_kernel(const float* __restrict__ x, const float* __restrict__ cb,
                float* __restrict__ sample, float* __restrict__ code,
                float* __restrict__ logit) {
  __shared__ __align__(16) float s_cb[KK * DD];   // 32 KB
  __shared__ __align__(16) float s_c2[KK];        // 1 KB
  __shared__ int s_wb[256];                       // 1 KB

  const int t  = threadIdx.x;
  const int b  = blockIdx.x;             // 1024 blocks
  const int nm = b >> 4;
  const int m  = nm & 3;
  const int hw = ((b & 15) << 8) + t;
  const int gp = (nm << 12) + hw;

  const float* cbm = cb + (size_t)m * (KK * DD);

  // stage codebook -> LDS
  {
    const float4* src = (const float4*)cbm;
    float4* dst = (float4*)s_cb;
    #pragma unroll
    for (int i = 0; i < 8; i++)
      dst[t + 256 * i] = src[t + 256 * i];
  }

  // x[d] -> VGPRs
  const float* xp = x + ((size_t)(nm * 32)) * 4096 + hw;
  float xv[DD];
  #pragma unroll
  for (int d = 0; d < DD; d++) xv[d] = xp[(size_t)d * 4096];

  const float x2 = sumsq_unfused(xv);

  // c2 row k=t (validated unfused chain)
  {
    const float4* rp = (const float4*)(cbm + t * DD);
    float cr[DD];
    #pragma unroll
    for (int j = 0; j < 8; j++) {
      float4 q = rp[j];
      cr[4*j+0] = q.x; cr[4*j+1] = q.y; cr[4*j+2] = q.z; cr[4*j+3] = q.w;
    }
    s_c2[t] = sumsq_unfused(cr);
  }
  __syncthreads();

  float* lrow = logit + ((size_t)gp << 8);
  float best = -__builtin_inff(), second = -__builtin_inff();
  int wb = 0;
  const uint32_t lbase = (uint32_t)gp << 8;

  #pragma unroll 1
  for (int kc = 0; kc < KK; kc += 16) {
    float L[16];
    #pragma unroll
    for (int g4 = 0; g4 < 16; g4 += 4) {
      const int k0 = kc + g4;
      const float4 c2q = *(const float4*)(s_c2 + k0);
      const float4* r0 = (const float4*)(s_cb + (size_t)(k0 + 0) * DD);
      const float4* r1 = (const float4*)(s_cb + (size_t)(k0 + 1) * DD);
      const float4* r2 = (const float4*)(s_cb + (size_t)(k0 + 2) * DD);
      const float4* r3 = (const float4*)(s_cb + (size_t)(k0 + 3) * DD);

      // 4 independent FUSED ascending fma chains (validated order)
      float i0 = 0.0f, i1 = 0.0f, i2 = 0.0f, i3 = 0.0f;
      #pragma unroll
      for (int j = 0; j < 8; j++) {
        float4 q0 = r0[j], q1 = r1[j], q2 = r2[j], q3 = r3[j];
        i0 = __builtin_fmaf(xv[4*j+0], q0.x, i0);
        i1 = __builtin_fmaf(xv[4*j+0], q1.x, i1);
        i2 = __builtin_fmaf(xv[4*j+0], q2.x, i2);
        i3 = __builtin_fmaf(xv[4*j+0], q3.x, i3);
        i0 = __builtin_fmaf(xv[4*j+1], q0.y, i0);
        i1 = __builtin_fmaf(xv[4*j+1], q1.y, i1);
        i2 = __builtin_fmaf(xv[4*j+1], q2.y, i2);
        i3 = __builtin_fmaf(xv[4*j+1], q3.y, i3);
        i0 = __builtin_fmaf(xv[4*j+2], q0.z, i0);
        i1 = __builtin_fmaf(xv[4*j+2], q1.z, i1);
        i2 = __builtin_fmaf(xv[4*j+2], q2.z, i2);
        i3 = __builtin_fmaf(xv[4*j+2], q3.z, i3);
        i0 = __builtin_fmaf(xv[4*j+3], q0.w, i0);
        i1 = __builtin_fmaf(xv[4*j+3], q1.w, i1);
        i2 = __builtin_fmaf(xv[4*j+3], q2.w, i2);
        i3 = __builtin_fmaf(xv[4*j+3], q3.w, i3);
      }

      float d0 = (x2 + c2q.x) - 2.0f * i0;
      float d1 = (x2 + c2q.y) - 2.0f * i1;
      float d2 = (x2 + c2q.z) - 2.0f * i2;
      float d3 = (x2 + c2q.w) - 2.0f * i3;
      float L0 = plog_xla(d0);     // logit stays bit-exact (validated)
      float L1 = plog_xla(d1);
      float L2 = plog_xla(d2);
      float L3 = plog_xla(d3);
      L[g4+0] = L0; L[g4+1] = L1; L[g4+2] = L2; L[g4+3] = L3;

      uint32_t a0,a1,b0,b1,c0,c1,e0,e1;
      threefry2x32(0u, 42u, 0u, lbase | (uint32_t)(k0 + 0), a0, a1);
      threefry2x32(0u, 42u, 0u, lbase | (uint32_t)(k0 + 1), b0, b1);
      threefry2x32(0u, 42u, 0u, lbase | (uint32_t)(k0 + 2), c0, c1);
      threefry2x32(0u, 42u, 0u, lbase | (uint32_t)(k0 + 3), e0, e1);
      float p0 = gumbel_fast(a0 ^ a1) + L0;
      float p1 = gumbel_fast(b0 ^ b1) + L1;
      float p2 = gumbel_fast(c0 ^ c1) + L2;
      float p3 = gumbel_fast(e0 ^ e1) + L3;

      // ascending strict > == first-occurrence; track top-2 for certification
      if (p0 > best) { second = best; best = p0; wb = k0 + 0; } else if (p0 > second) second = p0;
      if (p1 > best) { second = best; best = p1; wb = k0 + 1; } else if (p1 > second) second = p1;
      if (p2 > best) { second = best; best = p2; wb = k0 + 2; } else if (p2 > second) second = p2;
      if (p3 > best) { second = best; best = p3; wb = k0 + 3; } else if (p3 > second) second = p3;
    }
    // 64B burst: 4 x dwordx4 back-to-back (full-line coverage, R4 pattern)
    float4* dst = (float4*)(lrow + kc);
    dst[0] = make_float4(L[0],  L[1],  L[2],  L[3]);
    dst[1] = make_float4(L[4],  L[5],  L[6],  L[7]);
    dst[2] = make_float4(L[8],  L[9],  L[10], L[11]);
    dst[3] = make_float4(L[12], L[13], L[14], L[15]);
  }

  // certification: if top-2 margin too small, redo this pixel exactly (rare)
  if (!(best - second > MARGIN)) {
    float bb = -__builtin_inff();
    int wbb = 0;
    for (int k = 0; k < KK; k++) {
      const float4* rp = (const float4*)(s_cb + (size_t)k * DD);
      float inter = 0.0f;
      #pragma unroll
      for (int j = 0; j < 8; j++) {
        float4 q = rp[j];
        inter = __builtin_fmaf(xv[4*j+0], q.x, inter);
        inter = __builtin_fmaf(xv[4*j+1], q.y, inter);
        inter = __builtin_fmaf(xv[4*j+2], q.z, inter);
        inter = __builtin_fmaf(xv[4*j+3], q.w, inter);
      }
      float d = (x2 + s_c2[k]) - 2.0f * inter;
      float Lk = plog_xla(d);
      uint32_t v0, v1;
      threefry2x32(0u, 42u, 0u, lbase | (uint32_t)k, v0, v1);
      float phi = gumbel_from_bits(v0 ^ v1) + Lk;   // fully exact (validated)
      if (phi > bb) { bb = phi; wbb = k; }
    }
    wb = wbb;
  }

  code[gp] = (float)wb;
  s_wb[t] = wb;
  __syncthreads();

  // cooperative coalesced one-hot sample write
  const int lane = t & 63, wv = t >> 6;
  const int pbase = (nm << 12) + ((b & 15) << 8);
  const int k0 = lane << 2;
  for (int r = wv * 64; r < (wv + 1) * 64; r++) {
    const int w = s_wb[r];
    float4 v;
    v.x = (w == k0 + 0) ? 1.0f : 0.0f;
    v.y = (w == k0 + 1) ? 1.0f : 0.0f;
    v.z = (w == k0 + 2) ? 1.0f : 0.0f;
    v.w = (w == k0 + 3) ? 1.0f : 0.0f;
    ((float4*)(sample + (((size_t)(pbase + r)) << 8)))[lane] = v;
  }
}

extern "C" void kernel_launch(void* const* d_in, const int* in_sizes, int n_in,
                              void* d_out, int out_size, void* d_ws, size_t ws_size,
                              hipStream_t stream) {
  const float* x  = (const float*)d_in[0];
  const float* cb = (const float*)d_in[1];

  float* out_f  = (float*)d_out;
  float* sample = out_f;                       // 67108864
  float* code   = out_f + 67108864;            // 262144 (as float)
  float* logit  = out_f + 67108864 + 262144;   // 67108864

  mcq_kernel<<<1024, 256, 0, stream>>>(x, cb, sample, code, logit);
}

// Round 8
// 559.377 us; speedup vs baseline: 1.3972x; 1.3972x over previous
//
#include <hip/hip_runtime.h>
#include <stdint.h>

// N=16, M=4, D=32, K=256, H=64, W=64 ; P = 262144 pixels
// outputs (concat, read back as f32): sample (P*256), code (P, as float), logit (P*256)

#define TINY_F 1.17549435082228750797e-38f
#define LN2F   0.69314718055994530942f

// XLA:CPU vectorized log (GenerateVF32Log / Eigen plog), UNFUSED mul+add.
// Bit-exactness validated round 2 (code absmax == 0). DO NOT TOUCH.
__device__ __forceinline__ float plog_xla(float xin) {
  #pragma clang fp contract(off)
  uint32_t ix = __float_as_uint(xin);
  int e_i = (int)(ix >> 23) - 126;
  float x = __uint_as_float((ix & 0x007FFFFFu) | 0x3F000000u);
  float e = (float)e_i;
  bool lt = x < 0.707106781186547524f;
  float tmp = lt ? x : 0.0f;
  x = x - 1.0f;
  e = e - (lt ? 1.0f : 0.0f);
  x = x + tmp;
  float z  = x * x;
  float x3 = z * x;
  float y  =  7.0376836292e-2f * x + (-1.1514610310e-1f);
  float y1 = -1.2420140846e-1f * x +   1.4249322787e-1f;
  float y2 =  2.0000714765e-1f * x + (-2.4999993993e-1f);
  y  = y  * x +   1.1676998740e-1f;
  y1 = y1 * x + (-1.6668057665e-1f);
  y2 = y2 * x +   3.3333331174e-1f;
  y  = y * x3 + y1;
  y  = y * x3 + y2;
  y  = y * x3;
  y  = y + e * (-2.12194440e-4f);
  x  = x - 0.5f * z;
  x  = x + y;
  x  = x + e * 0.693359375f;
  return x;
}

// UNFUSED ascending square-sum (XLA reduce order). Pragma at body start.
__device__ __forceinline__ float sumsq_unfused(const float* v) {
  #pragma clang fp contract(off)
  float a = 0.0f;
  #pragma unroll
  for (int d = 0; d < 32; d++) a = a + v[d] * v[d];
  return a;
}

__device__ __forceinline__ void threefry2x32(uint32_t k0, uint32_t k1,
                                             uint32_t x0, uint32_t x1,
                                             uint32_t& o0, uint32_t& o1) {
  uint32_t ks2 = k0 ^ k1 ^ 0x1BD11BDAu;
  x0 += k0; x1 += k1;
#define TF_RND(r) { x0 += x1; x1 = (x1 << (r)) | (x1 >> (32 - (r))); x1 ^= x0; }
  TF_RND(13) TF_RND(15) TF_RND(26) TF_RND(6)
  x0 += k1; x1 += ks2 + 1u;
  TF_RND(17) TF_RND(29) TF_RND(16) TF_RND(24)
  x0 += ks2; x1 += k0 + 2u;
  TF_RND(13) TF_RND(15) TF_RND(26) TF_RND(6)
  x0 += k0; x1 += k1 + 3u;
  TF_RND(17) TF_RND(29) TF_RND(16) TF_RND(24)
  x0 += k1; x1 += ks2 + 4u;
  TF_RND(13) TF_RND(15) TF_RND(26) TF_RND(6)
  x0 += ks2; x1 += k0 + 5u;
#undef TF_RND
  o0 = x0; o1 = x1;
}

// EXACT gumbel (validated R2) — slow path only.
__device__ __forceinline__ float gumbel_from_bits(uint32_t bits) {
  uint32_t mant = bits >> 9;
  float f = __uint_as_float(0x3F800000u | mant) - 1.0f;
  float u = mant ? f : TINY_F;
  float t = -plog_xla(u);
  return -plog_xla(t);
}

// FAST gumbel via v_log_f32 (argmax scoring only; certified by margin test).
__device__ __forceinline__ float gumbel_fast(uint32_t bits) {
  uint32_t mant = bits >> 9;
  float f = __uint_as_float(0x3F800000u | mant) - 1.0f;
  float u = mant ? f : TINY_F;
  float t = -(__log2f(u) * LN2F);
  return -(__log2f(t) * LN2F);
}

constexpr int KK = 256;
constexpr int DD = 32;
#define MARGIN 2.0e-4f

__global__ __launch_bounds__(256, 2)
void mcq_kernel(const float* __restrict__ x, const float* __restrict__ cb,
                float* __restrict__ sample, float* __restrict__ code,
                float* __restrict__ logit) {
  __shared__ __align__(16) float s_cb[KK * DD];   // 32 KB
  __shared__ __align__(16) float s_c2[KK];        // 1 KB
  __shared__ int s_wb[256];                       // 1 KB

  const int t  = threadIdx.x;
  const int b  = blockIdx.x;             // 1024 blocks
  const int nm = b >> 4;
  const int m  = nm & 3;
  const int hw = ((b & 15) << 8) + t;
  const int gp = (nm << 12) + hw;

  const float* cbm = cb + (size_t)m * (KK * DD);

  // stage codebook -> LDS
  {
    const float4* src = (const float4*)cbm;
    float4* dst = (float4*)s_cb;
    #pragma unroll
    for (int i = 0; i < 8; i++)
      dst[t + 256 * i] = src[t + 256 * i];
  }

  // x[d] -> VGPRs
  const float* xp = x + ((size_t)(nm * 32)) * 4096 + hw;
  float xv[DD];
  #pragma unroll
  for (int d = 0; d < DD; d++) xv[d] = xp[(size_t)d * 4096];

  const float x2 = sumsq_unfused(xv);

  // c2 row k=t (validated unfused chain)
  {
    const float4* rp = (const float4*)(cbm + t * DD);
    float cr[DD];
    #pragma unroll
    for (int j = 0; j < 8; j++) {
      float4 q = rp[j];
      cr[4*j+0] = q.x; cr[4*j+1] = q.y; cr[4*j+2] = q.z; cr[4*j+3] = q.w;
    }
    s_c2[t] = sumsq_unfused(cr);
  }
  __syncthreads();

  float* lrow = logit + ((size_t)gp << 8);
  float best = -__builtin_inff(), second = -__builtin_inff();
  int wb = 0;
  const uint32_t lbase = (uint32_t)gp << 8;

  // One 4-wide interleaved group of k0..k0+3. Math identical to R7.
#define GROUP(G4, LQ)                                                          \
  {                                                                            \
    const int k0 = kc + (G4);                                                  \
    const float4 c2q = *(const float4*)(s_c2 + k0);                            \
    const float4* r0 = (const float4*)(s_cb + (size_t)(k0 + 0) * DD);          \
    const float4* r1 = (const float4*)(s_cb + (size_t)(k0 + 1) * DD);          \
    const float4* r2 = (const float4*)(s_cb + (size_t)(k0 + 2) * DD);          \
    const float4* r3 = (const float4*)(s_cb + (size_t)(k0 + 3) * DD);          \
    float i0 = 0.0f, i1 = 0.0f, i2 = 0.0f, i3 = 0.0f;                          \
    _Pragma("unroll")                                                          \
    for (int j = 0; j < 8; j++) {                                              \
      float4 q0 = r0[j], q1 = r1[j], q2 = r2[j], q3 = r3[j];                   \
      i0 = __builtin_fmaf(xv[4*j+0], q0.x, i0);                                \
      i1 = __builtin_fmaf(xv[4*j+0], q1.x, i1);                                \
      i2 = __builtin_fmaf(xv[4*j+0], q2.x, i2);                                \
      i3 = __builtin_fmaf(xv[4*j+0], q3.x, i3);                                \
      i0 = __builtin_fmaf(xv[4*j+1], q0.y, i0);                                \
      i1 = __builtin_fmaf(xv[4*j+1], q1.y, i1);                                \
      i2 = __builtin_fmaf(xv[4*j+1], q2.y, i2);                                \
      i3 = __builtin_fmaf(xv[4*j+1], q3.y, i3);                                \
      i0 = __builtin_fmaf(xv[4*j+2], q0.z, i0);                                \
      i1 = __builtin_fmaf(xv[4*j+2], q1.z, i1);                                \
      i2 = __builtin_fmaf(xv[4*j+2], q2.z, i2);                                \
      i3 = __builtin_fmaf(xv[4*j+2], q3.z, i3);                                \
      i0 = __builtin_fmaf(xv[4*j+3], q0.w, i0);                                \
      i1 = __builtin_fmaf(xv[4*j+3], q1.w, i1);                                \
      i2 = __builtin_fmaf(xv[4*j+3], q2.w, i2);                                \
      i3 = __builtin_fmaf(xv[4*j+3], q3.w, i3);                                \
    }                                                                          \
    float d0 = (x2 + c2q.x) - 2.0f * i0;                                       \
    float d1 = (x2 + c2q.y) - 2.0f * i1;                                       \
    float d2 = (x2 + c2q.z) - 2.0f * i2;                                       \
    float d3 = (x2 + c2q.w) - 2.0f * i3;                                       \
    float L0 = plog_xla(d0);                                                   \
    float L1 = plog_xla(d1);                                                   \
    float L2 = plog_xla(d2);                                                   \
    float L3 = plog_xla(d3);                                                   \
    uint32_t a0,a1,b0,b1,c0,c1,e0,e1;                                          \
    threefry2x32(0u, 42u, 0u, lbase | (uint32_t)(k0 + 0), a0, a1);             \
    threefry2x32(0u, 42u, 0u, lbase | (uint32_t)(k0 + 1), b0, b1);             \
    threefry2x32(0u, 42u, 0u, lbase | (uint32_t)(k0 + 2), c0, c1);             \
    threefry2x32(0u, 42u, 0u, lbase | (uint32_t)(k0 + 3), e0, e1);             \
    float p0 = gumbel_fast(a0 ^ a1) + L0;                                      \
    float p1 = gumbel_fast(b0 ^ b1) + L1;                                      \
    float p2 = gumbel_fast(c0 ^ c1) + L2;                                      \
    float p3 = gumbel_fast(e0 ^ e1) + L3;                                      \
    if (p0 > best) { second = best; best = p0; wb = k0 + 0; } else if (p0 > second) second = p0; \
    if (p1 > best) { second = best; best = p1; wb = k0 + 1; } else if (p1 > second) second = p1; \
    if (p2 > best) { second = best; best = p2; wb = k0 + 2; } else if (p2 > second) second = p2; \
    if (p3 > best) { second = best; best = p3; wb = k0 + 3; } else if (p3 > second) second = p3; \
    LQ = make_float4(L0, L1, L2, L3);                                          \
  }

  #pragma unroll 1
  for (int kc = 0; kc < KK; kc += 16) {
    float4 Lq0, Lq1, Lq2, Lq3;        // named regs, never an indexed array
    GROUP(0,  Lq0)
    GROUP(4,  Lq1)
    GROUP(8,  Lq2)
    GROUP(12, Lq3)
    // 64B burst: 4 x dwordx4 back-to-back (full-line coverage)
    float4* dst = (float4*)(lrow + kc);
    dst[0] = Lq0; dst[1] = Lq1; dst[2] = Lq2; dst[3] = Lq3;
  }
#undef GROUP

  // certification: if top-2 margin too small, redo this pixel exactly (rare)
  if (!(best - second > MARGIN)) {
    float bb = -__builtin_inff();
    int wbb = 0;
    for (int k = 0; k < KK; k++) {
      const float4* rp = (const float4*)(s_cb + (size_t)k * DD);
      float inter = 0.0f;
      #pragma unroll
      for (int j = 0; j < 8; j++) {
        float4 q = rp[j];
        inter = __builtin_fmaf(xv[4*j+0], q.x, inter);
        inter = __builtin_fmaf(xv[4*j+1], q.y, inter);
        inter = __builtin_fmaf(xv[4*j+2], q.z, inter);
        inter = __builtin_fmaf(xv[4*j+3], q.w, inter);
      }
      float d = (x2 + s_c2[k]) - 2.0f * inter;
      float Lk = plog_xla(d);
      uint32_t v0, v1;
      threefry2x32(0u, 42u, 0u, lbase | (uint32_t)k, v0, v1);
      float phi = gumbel_from_bits(v0 ^ v1) + Lk;   // fully exact (validated)
      if (phi > bb) { bb = phi; wbb = k; }
    }
    wb = wbb;
  }

  code[gp] = (float)wb;
  s_wb[t] = wb;
  __syncthreads();

  // cooperative coalesced one-hot sample write
  const int lane = t & 63, wv = t >> 6;
  const int pbase = (nm << 12) + ((b & 15) << 8);
  const int k0 = lane << 2;
  for (int r = wv * 64; r < (wv + 1) * 64; r++) {
    const int w = s_wb[r];
    float4 v;
    v.x = (w == k0 + 0) ? 1.0f : 0.0f;
    v.y = (w == k0 + 1) ? 1.0f : 0.0f;
    v.z = (w == k0 + 2) ? 1.0f : 0.0f;
    v.w = (w == k0 + 3) ? 1.0f : 0.0f;
    ((float4*)(sample + (((size_t)(pbase + r)) << 8)))[lane] = v;
  }
}

extern "C" void kernel_launch(void* const* d_in, const int* in_sizes, int n_in,
                              void* d_out, int out_size, void* d_ws, size_t ws_size,
                              hipStream_t stream) {
  const float* x  = (const float*)d_in[0];
  const float* cb = (const float*)d_in[1];

  float* out_f  = (float*)d_out;
  float* sample = out_f;                       // 67108864
  float* code   = out_f + 67108864;            // 262144 (as float)
  float* logit  = out_f + 67108864 + 262144;   // 67108864

  mcq_kernel<<<1024, 256, 0, stream>>>(x, cb, sample, code, logit);
}

// Round 9
// 472.454 us; speedup vs baseline: 1.6542x; 1.1840x over previous
//
#include <hip/hip_runtime.h>
#include <stdint.h>

// N=16, M=4, D=32, K=256, H=64, W=64 ; P = 262144 pixels
// outputs (concat, read back as f32): sample (P*256), code (P, as float), logit (P*256)

#define TINY_F 1.17549435082228750797e-38f
#define LN2F   0.69314718055994530942f

// XLA:CPU vectorized log (GenerateVF32Log / Eigen plog), UNFUSED mul+add.
// Bit-exactness validated round 2 (code absmax == 0). Used in exact fallback only.
__device__ __forceinline__ float plog_xla(float xin) {
  #pragma clang fp contract(off)
  uint32_t ix = __float_as_uint(xin);
  int e_i = (int)(ix >> 23) - 126;
  float x = __uint_as_float((ix & 0x007FFFFFu) | 0x3F000000u);
  float e = (float)e_i;
  bool lt = x < 0.707106781186547524f;
  float tmp = lt ? x : 0.0f;
  x = x - 1.0f;
  e = e - (lt ? 1.0f : 0.0f);
  x = x + tmp;
  float z  = x * x;
  float x3 = z * x;
  float y  =  7.0376836292e-2f * x + (-1.1514610310e-1f);
  float y1 = -1.2420140846e-1f * x +   1.4249322787e-1f;
  float y2 =  2.0000714765e-1f * x + (-2.4999993993e-1f);
  y  = y  * x +   1.1676998740e-1f;
  y1 = y1 * x + (-1.6668057665e-1f);
  y2 = y2 * x +   3.3333331174e-1f;
  y  = y * x3 + y1;
  y  = y * x3 + y2;
  y  = y * x3;
  y  = y + e * (-2.12194440e-4f);
  x  = x - 0.5f * z;
  x  = x + y;
  x  = x + e * 0.693359375f;
  return x;
}

// UNFUSED ascending square-sum (XLA reduce order). Pragma at body start.
__device__ __forceinline__ float sumsq_unfused(const float* v) {
  #pragma clang fp contract(off)
  float a = 0.0f;
  #pragma unroll
  for (int d = 0; d < 32; d++) a = a + v[d] * v[d];
  return a;
}

__device__ __forceinline__ void threefry2x32(uint32_t k0, uint32_t k1,
                                             uint32_t x0, uint32_t x1,
                                             uint32_t& o0, uint32_t& o1) {
  uint32_t ks2 = k0 ^ k1 ^ 0x1BD11BDAu;
  x0 += k0; x1 += k1;
#define TF_RND(r) { x0 += x1; x1 = (x1 << (r)) | (x1 >> (32 - (r))); x1 ^= x0; }
  TF_RND(13) TF_RND(15) TF_RND(26) TF_RND(6)
  x0 += k1; x1 += ks2 + 1u;
  TF_RND(17) TF_RND(29) TF_RND(16) TF_RND(24)
  x0 += ks2; x1 += k0 + 2u;
  TF_RND(13) TF_RND(15) TF_RND(26) TF_RND(6)
  x0 += k0; x1 += k1 + 3u;
  TF_RND(17) TF_RND(29) TF_RND(16) TF_RND(24)
  x0 += k1; x1 += ks2 + 4u;
  TF_RND(13) TF_RND(15) TF_RND(26) TF_RND(6)
  x0 += ks2; x1 += k0 + 5u;
#undef TF_RND
  o0 = x0; o1 = x1;
}

// EXACT gumbel (validated R2) — fallback only.
__device__ __forceinline__ float gumbel_from_bits(uint32_t bits) {
  uint32_t mant = bits >> 9;
  float f = __uint_as_float(0x3F800000u | mant) - 1.0f;
  float u = mant ? f : TINY_F;
  float t = -plog_xla(u);
  return -plog_xla(t);
}

// FAST gumbel via v_log_f32 (argmax scoring only; certified by margin test).
__device__ __forceinline__ float gumbel_fast(uint32_t bits) {
  uint32_t mant = bits >> 9;
  float f = __uint_as_float(0x3F800000u | mant) - 1.0f;
  float u = mant ? f : TINY_F;
  float t = -(__log2f(u) * LN2F);
  return -(__log2f(t) * LN2F);
}

constexpr int KK = 256;
constexpr int DD = 32;
#define MARGIN 2.0e-4f

__global__ __launch_bounds__(256, 4)
void mcq_kernel(const float* __restrict__ x, const float* __restrict__ cb,
                float* __restrict__ sample, float* __restrict__ code,
                float* __restrict__ logit) {
  __shared__ __align__(16) float s_cb[KK * DD];   // 32 KB
  __shared__ __align__(16) float s_c2[KK];        // 1 KB
  __shared__ int s_wb[256];                       // 1 KB

  const int t  = threadIdx.x;
  const int b  = blockIdx.x;             // 1024 blocks
  const int nm = b >> 4;
  const int m  = nm & 3;
  const int hw = ((b & 15) << 8) + t;
  const int gp = (nm << 12) + hw;

  const float* cbm = cb + (size_t)m * (KK * DD);

  // stage codebook -> LDS
  {
    const float4* src = (const float4*)cbm;
    float4* dst = (float4*)s_cb;
    #pragma unroll
    for (int i = 0; i < 8; i++)
      dst[t + 256 * i] = src[t + 256 * i];
  }

  // x[d] -> VGPRs
  const float* xp = x + ((size_t)(nm * 32)) * 4096 + hw;
  float xv[DD];
  #pragma unroll
  for (int d = 0; d < DD; d++) xv[d] = xp[(size_t)d * 4096];

  const float x2 = sumsq_unfused(xv);

  // c2 row k=t (validated unfused chain)
  {
    const float4* rp = (const float4*)(cbm + t * DD);
    float cr[DD];
    #pragma unroll
    for (int j = 0; j < 8; j++) {
      float4 q = rp[j];
      cr[4*j+0] = q.x; cr[4*j+1] = q.y; cr[4*j+2] = q.z; cr[4*j+3] = q.w;
    }
    s_c2[t] = sumsq_unfused(cr);
  }
  __syncthreads();

  float* lrow = logit + ((size_t)gp << 8);
  float best = -__builtin_inff(), second = -__builtin_inff();
  int wb = 0;
  const uint32_t lbase = (uint32_t)gp << 8;

  // One 4-wide interleaved group of k0..k0+3. dist math identical to R2-validated.
  // Logit OUTPUT now hw-log (abs delta vs plog ~1e-6, threshold ~0.1).
#define GROUP(G4, LQ)                                                          \
  {                                                                            \
    const int k0 = kc + (G4);                                                  \
    const float4 c2q = *(const float4*)(s_c2 + k0);                            \
    const float4* r0 = (const float4*)(s_cb + (size_t)(k0 + 0) * DD);          \
    const float4* r1 = (const float4*)(s_cb + (size_t)(k0 + 1) * DD);          \
    const float4* r2 = (const float4*)(s_cb + (size_t)(k0 + 2) * DD);          \
    const float4* r3 = (const float4*)(s_cb + (size_t)(k0 + 3) * DD);          \
    float i0 = 0.0f, i1 = 0.0f, i2 = 0.0f, i3 = 0.0f;                          \
    _Pragma("unroll")                                                          \
    for (int j = 0; j < 8; j++) {                                              \
      float4 q0 = r0[j], q1 = r1[j], q2 = r2[j], q3 = r3[j];                   \
      i0 = __builtin_fmaf(xv[4*j+0], q0.x, i0);                                \
      i1 = __builtin_fmaf(xv[4*j+0], q1.x, i1);                                \
      i2 = __builtin_fmaf(xv[4*j+0], q2.x, i2);                                \
      i3 = __builtin_fmaf(xv[4*j+0], q3.x, i3);                                \
      i0 = __builtin_fmaf(xv[4*j+1], q0.y, i0);                                \
      i1 = __builtin_fmaf(xv[4*j+1], q1.y, i1);                                \
      i2 = __builtin_fmaf(xv[4*j+1], q2.y, i2);                                \
      i3 = __builtin_fmaf(xv[4*j+1], q3.y, i3);                                \
      i0 = __builtin_fmaf(xv[4*j+2], q0.z, i0);                                \
      i1 = __builtin_fmaf(xv[4*j+2], q1.z, i1);                                \
      i2 = __builtin_fmaf(xv[4*j+2], q2.z, i2);                                \
      i3 = __builtin_fmaf(xv[4*j+2], q3.z, i3);                                \
      i0 = __builtin_fmaf(xv[4*j+3], q0.w, i0);                                \
      i1 = __builtin_fmaf(xv[4*j+3], q1.w, i1);                                \
      i2 = __builtin_fmaf(xv[4*j+3], q2.w, i2);                                \
      i3 = __builtin_fmaf(xv[4*j+3], q3.w, i3);                                \
    }                                                                          \
    float d0 = (x2 + c2q.x) - 2.0f * i0;                                       \
    float d1 = (x2 + c2q.y) - 2.0f * i1;                                       \
    float d2 = (x2 + c2q.z) - 2.0f * i2;                                       \
    float d3 = (x2 + c2q.w) - 2.0f * i3;                                       \
    float L0 = __log2f(d0) * LN2F;                                             \
    float L1 = __log2f(d1) * LN2F;                                             \
    float L2 = __log2f(d2) * LN2F;                                             \
    float L3 = __log2f(d3) * LN2F;                                             \
    uint32_t a0,a1,b0,b1,c0,c1,e0,e1;                                          \
    threefry2x32(0u, 42u, 0u, lbase | (uint32_t)(k0 + 0), a0, a1);             \
    threefry2x32(0u, 42u, 0u, lbase | (uint32_t)(k0 + 1), b0, b1);             \
    threefry2x32(0u, 42u, 0u, lbase | (uint32_t)(k0 + 2), c0, c1);             \
    threefry2x32(0u, 42u, 0u, lbase | (uint32_t)(k0 + 3), e0, e1);             \
    float p0 = gumbel_fast(a0 ^ a1) + L0;                                      \
    float p1 = gumbel_fast(b0 ^ b1) + L1;                                      \
    float p2 = gumbel_fast(c0 ^ c1) + L2;                                      \
    float p3 = gumbel_fast(e0 ^ e1) + L3;                                      \
    if (p0 > best) { second = best; best = p0; wb = k0 + 0; } else if (p0 > second) second = p0; \
    if (p1 > best) { second = best; best = p1; wb = k0 + 1; } else if (p1 > second) second = p1; \
    if (p2 > best) { second = best; best = p2; wb = k0 + 2; } else if (p2 > second) second = p2; \
    if (p3 > best) { second = best; best = p3; wb = k0 + 3; } else if (p3 > second) second = p3; \
    LQ = make_float4(L0, L1, L2, L3);                                          \
  }

  #pragma unroll 1
  for (int kc = 0; kc < KK; kc += 16) {
    float4 Lq0, Lq1, Lq2, Lq3;        // named regs, never an indexed array
    GROUP(0,  Lq0)
    GROUP(4,  Lq1)
    GROUP(8,  Lq2)
    GROUP(12, Lq3)
    // 64B burst: 4 x dwordx4 back-to-back (full-line coverage)
    float4* dst = (float4*)(lrow + kc);
    dst[0] = Lq0; dst[1] = Lq1; dst[2] = Lq2; dst[3] = Lq3;
  }
#undef GROUP

  // certification: if top-2 margin too small, redo this pixel with the fully
  // exact validated path (plog logit + plog gumbel). Rare (~1e-4 of pixels).
  if (!(best - second > MARGIN)) {
    float bb = -__builtin_inff();
    int wbb = 0;
    for (int k = 0; k < KK; k++) {
      const float4* rp = (const float4*)(s_cb + (size_t)k * DD);
      float inter = 0.0f;
      #pragma unroll
      for (int j = 0; j < 8; j++) {
        float4 q = rp[j];
        inter = __builtin_fmaf(xv[4*j+0], q.x, inter);
        inter = __builtin_fmaf(xv[4*j+1], q.y, inter);
        inter = __builtin_fmaf(xv[4*j+2], q.z, inter);
        inter = __builtin_fmaf(xv[4*j+3], q.w, inter);
      }
      float d = (x2 + s_c2[k]) - 2.0f * inter;
      float Lk = plog_xla(d);
      uint32_t v0, v1;
      threefry2x32(0u, 42u, 0u, lbase | (uint32_t)k, v0, v1);
      float phi = gumbel_from_bits(v0 ^ v1) + Lk;   // fully exact (validated)
      if (phi > bb) { bb = phi; wbb = k; }
    }
    wb = wbb;
  }

  code[gp] = (float)wb;
  s_wb[t] = wb;
  __syncthreads();

  // cooperative coalesced one-hot sample write
  const int lane = t & 63, wv = t >> 6;
  const int pbase = (nm << 12) + ((b & 15) << 8);
  const int k0 = lane << 2;
  for (int r = wv * 64; r < (wv + 1) * 64; r++) {
    const int w = s_wb[r];
    float4 v;
    v.x = (w == k0 + 0) ? 1.0f : 0.0f;
    v.y = (w == k0 + 1) ? 1.0f : 0.0f;
    v.z = (w == k0 + 2) ? 1.0f : 0.0f;
    v.w = (w == k0 + 3) ? 1.0f : 0.0f;
    ((float4*)(sample + (((size_t)(pbase + r)) << 8)))[lane] = v;
  }
}

extern "C" void kernel_launch(void* const* d_in, const int* in_sizes, int n_in,
                              void* d_out, int out_size, void* d_ws, size_t ws_size,
                              hipStream_t stream) {
  const float* x  = (const float*)d_in[0];
  const float* cb = (const float*)d_in[1];

  float* out_f  = (float*)d_out;
  float* sample = out_f;                       // 67108864
  float* code   = out_f + 67108864;            // 262144 (as float)
  float* logit  = out_f + 67108864 + 262144;   // 67108864

  mcq_kernel<<<1024, 256, 0, stream>>>(x, cb, sample, code, logit);
}

// Round 10
// 341.985 us; speedup vs baseline: 2.2853x; 1.3815x over previous
//
#include <hip/hip_runtime.h>
#include <stdint.h>

// N=16, M=4, D=32, K=256, H=64, W=64 ; P = 262144 pixels
// outputs (concat, read back as f32): sample (P*256), code (P, as float), logit (P*256)
// d_ws: uint2[2][P] = (exact phi bits, winner k) per (half, pixel)

#define TINY_F 1.17549435082228750797e-38f
#define LN2F   0.69314718055994530942f
#define MARGIN 2.0e-4f

constexpr int KK = 256;
constexpr int DD = 32;
constexpr int HALF = 128;
constexpr int P_TOT = 262144;

// XLA:CPU vectorized log (GenerateVF32Log / Eigen plog), UNFUSED mul+add.
// Bit-exactness validated round 2 (code absmax == 0). Exact path only.
__device__ __forceinline__ float plog_xla(float xin) {
  #pragma clang fp contract(off)
  uint32_t ix = __float_as_uint(xin);
  int e_i = (int)(ix >> 23) - 126;
  float x = __uint_as_float((ix & 0x007FFFFFu) | 0x3F000000u);
  float e = (float)e_i;
  bool lt = x < 0.707106781186547524f;
  float tmp = lt ? x : 0.0f;
  x = x - 1.0f;
  e = e - (lt ? 1.0f : 0.0f);
  x = x + tmp;
  float z  = x * x;
  float x3 = z * x;
  float y  =  7.0376836292e-2f * x + (-1.1514610310e-1f);
  float y1 = -1.2420140846e-1f * x +   1.4249322787e-1f;
  float y2 =  2.0000714765e-1f * x + (-2.4999993993e-1f);
  y  = y  * x +   1.1676998740e-1f;
  y1 = y1 * x + (-1.6668057665e-1f);
  y2 = y2 * x +   3.3333331174e-1f;
  y  = y * x3 + y1;
  y  = y * x3 + y2;
  y  = y * x3;
  y  = y + e * (-2.12194440e-4f);
  x  = x - 0.5f * z;
  x  = x + y;
  x  = x + e * 0.693359375f;
  return x;
}

__device__ __forceinline__ float sumsq_unfused(const float* v) {
  #pragma clang fp contract(off)
  float a = 0.0f;
  #pragma unroll
  for (int d = 0; d < 32; d++) a = a + v[d] * v[d];
  return a;
}

__device__ __forceinline__ void threefry2x32(uint32_t k0, uint32_t k1,
                                             uint32_t x0, uint32_t x1,
                                             uint32_t& o0, uint32_t& o1) {
  uint32_t ks2 = k0 ^ k1 ^ 0x1BD11BDAu;
  x0 += k0; x1 += k1;
#define TF_RND(r) { x0 += x1; x1 = (x1 << (r)) | (x1 >> (32 - (r))); x1 ^= x0; }
  TF_RND(13) TF_RND(15) TF_RND(26) TF_RND(6)
  x0 += k1; x1 += ks2 + 1u;
  TF_RND(17) TF_RND(29) TF_RND(16) TF_RND(24)
  x0 += ks2; x1 += k0 + 2u;
  TF_RND(13) TF_RND(15) TF_RND(26) TF_RND(6)
  x0 += k0; x1 += k1 + 3u;
  TF_RND(17) TF_RND(29) TF_RND(16) TF_RND(24)
  x0 += k1; x1 += ks2 + 4u;
  TF_RND(13) TF_RND(15) TF_RND(26) TF_RND(6)
  x0 += ks2; x1 += k0 + 5u;
#undef TF_RND
  o0 = x0; o1 = x1;
}

// EXACT gumbel (validated R2).
__device__ __forceinline__ float gumbel_from_bits(uint32_t bits) {
  uint32_t mant = bits >> 9;
  float f = __uint_as_float(0x3F800000u | mant) - 1.0f;
  float u = mant ? f : TINY_F;
  float t = -plog_xla(u);
  return -plog_xla(t);
}

// FAST gumbel via v_log_f32 (scan only; certified by margin).
__device__ __forceinline__ float gumbel_fast(uint32_t bits) {
  uint32_t mant = bits >> 9;
  float f = __uint_as_float(0x3F800000u | mant) - 1.0f;
  float u = mant ? f : TINY_F;
  float t = -(__log2f(u) * LN2F);
  return -(__log2f(t) * LN2F);
}

// exact phi for local row kl (all-validated chains), from LDS half-codebook
#define EXACT_PHI(OUT, KL)                                                     \
  {                                                                            \
    const int _kl = (KL);                                                      \
    const float4* _rp = (const float4*)(s_cb2 + (size_t)_kl * DD);             \
    float _in = 0.0f;                                                          \
    _Pragma("unroll")                                                          \
    for (int _j = 0; _j < 8; _j++) {                                           \
      float4 _q = _rp[_j];                                                     \
      _in = __builtin_fmaf(xv[4*_j+0], _q.x, _in);                             \
      _in = __builtin_fmaf(xv[4*_j+1], _q.y, _in);                             \
      _in = __builtin_fmaf(xv[4*_j+2], _q.z, _in);                             \
      _in = __builtin_fmaf(xv[4*_j+3], _q.w, _in);                             \
    }                                                                          \
    float _d = (x2 + s_c2h[_kl]) - 2.0f * _in;                                 \
    float _L = plog_xla(_d);                                                   \
    uint32_t _v0, _v1;                                                         \
    threefry2x32(0u, 42u, 0u, lbase + (uint32_t)_kl, _v0, _v1);                \
    OUT = gumbel_from_bits(_v0 ^ _v1) + _L;                                    \
  }

__global__ __launch_bounds__(256, 8)
void mcq_main(const float* __restrict__ x, const float* __restrict__ cb,
              float* __restrict__ logit, uint2* __restrict__ ws) {
  __shared__ __align__(16) float s_cb2[HALF * DD];  // 16 KB
  __shared__ __align__(16) float s_c2h[HALF];       // 512 B

  const int t   = threadIdx.x;
  const int bid = blockIdx.x;          // 2048 blocks = (group g, half h)
  const int g   = bid >> 1;
  const int h   = bid & 1;
  const int nm  = g >> 4;
  const int m   = nm & 3;
  const int hw  = ((g & 15) << 8) + t;
  const int gp  = (nm << 12) + hw;     // global pixel

  const float* cbm = cb + (size_t)m * (KK * DD) + (size_t)h * (HALF * DD);

  // stage half codebook -> LDS (1024 float4, 4/thread)
  {
    const float4* src = (const float4*)cbm;
    float4* dst = (float4*)s_cb2;
    #pragma unroll
    for (int i = 0; i < 4; i++)
      dst[t + 256 * i] = src[t + 256 * i];
  }

  // x[d] -> VGPRs
  const float* xp = x + ((size_t)(nm * 32)) * 4096 + hw;
  float xv[DD];
  #pragma unroll
  for (int d = 0; d < DD; d++) xv[d] = xp[(size_t)d * 4096];

  const float x2 = sumsq_unfused(xv);

  // c2 for local rows 0..127 (validated unfused chain)
  if (t < HALF) {
    const float4* rp = (const float4*)(cbm + t * DD);
    float cr[DD];
    #pragma unroll
    for (int j = 0; j < 8; j++) {
      float4 q = rp[j];
      cr[4*j+0] = q.x; cr[4*j+1] = q.y; cr[4*j+2] = q.z; cr[4*j+3] = q.w;
    }
    s_c2h[t] = sumsq_unfused(cr);
  }
  __syncthreads();

  float* lrow = logit + ((size_t)gp << 8) + h * HALF;
  const uint32_t lbase = ((uint32_t)gp << 8) + (uint32_t)(h * HALF);

  float best = -__builtin_inff(), second = -__builtin_inff(), third = -__builtin_inff();
  int bi1 = 0, bi2 = 0;

  // 2-wide group over local rows kl, kl+1 (dist math identical to validated)
#define GROUP2(KL, LA, LB)                                                     \
  {                                                                            \
    const int kl = kc + (KL);                                                  \
    const float2 c2p = *(const float2*)(s_c2h + kl);                           \
    const float4* r0 = (const float4*)(s_cb2 + (size_t)kl * DD);               \
    const float4* r1 = r0 + 8;                                                 \
    float i0 = 0.0f, i1 = 0.0f;                                                \
    _Pragma("unroll")                                                          \
    for (int j = 0; j < 8; j++) {                                              \
      float4 q0 = r0[j], q1 = r1[j];                                           \
      i0 = __builtin_fmaf(xv[4*j+0], q0.x, i0);                                \
      i1 = __builtin_fmaf(xv[4*j+0], q1.x, i1);                                \
      i0 = __builtin_fmaf(xv[4*j+1], q0.y, i0);                                \
      i1 = __builtin_fmaf(xv[4*j+1], q1.y, i1);                                \
      i0 = __builtin_fmaf(xv[4*j+2], q0.z, i0);                                \
      i1 = __builtin_fmaf(xv[4*j+2], q1.z, i1);                                \
      i0 = __builtin_fmaf(xv[4*j+3], q0.w, i0);                                \
      i1 = __builtin_fmaf(xv[4*j+3], q1.w, i1);                                \
    }                                                                          \
    float d0 = (x2 + c2p.x) - 2.0f * i0;                                       \
    float d1 = (x2 + c2p.y) - 2.0f * i1;                                       \
    LA = __log2f(d0) * LN2F;                                                   \
    LB = __log2f(d1) * LN2F;                                                   \
    uint32_t a0, a1, b0, b1;                                                   \
    threefry2x32(0u, 42u, 0u, lbase + (uint32_t)kl,        a0, a1);            \
    threefry2x32(0u, 42u, 0u, lbase + (uint32_t)(kl + 1),  b0, b1);            \
    float p0 = gumbel_fast(a0 ^ a1) + LA;                                      \
    float p1 = gumbel_fast(b0 ^ b1) + LB;                                      \
    if (p0 > best) { third = second; second = best; bi2 = bi1; best = p0; bi1 = kl; }          \
    else if (p0 > second) { third = second; second = p0; bi2 = kl; }           \
    else if (p0 > third) third = p0;                                           \
    if (p1 > best) { third = second; second = best; bi2 = bi1; best = p1; bi1 = kl + 1; }      \
    else if (p1 > second) { third = second; second = p1; bi2 = kl + 1; }       \
    else if (p1 > third) third = p1;                                           \
  }

  #pragma unroll 1
  for (int kc = 0; kc < HALF; kc += 8) {
    float L0, L1, L2, L3, L4, L5, L6, L7;   // named regs only
    GROUP2(0, L0, L1)
    GROUP2(2, L2, L3)
    GROUP2(4, L4, L5)
    GROUP2(6, L6, L7)
    float4* dst = (float4*)(lrow + kc);     // 32B burst
    dst[0] = make_float4(L0, L1, L2, L3);
    dst[1] = make_float4(L4, L5, L6, L7);
  }
#undef GROUP2

  // resolve half-winner with exact phi (validated chains)
  int wbl; float fw;
  if (best - second > MARGIN) {
    wbl = bi1;
    EXACT_PHI(fw, wbl)
  } else if (best - third > MARGIN) {
    // true argmax certified within {bi1, bi2}
    int ka = bi1 < bi2 ? bi1 : bi2;
    int kb = bi1 < bi2 ? bi2 : bi1;
    float fa, fb;
    EXACT_PHI(fa, ka)
    EXACT_PHI(fb, kb)
    if (fb > fa) { wbl = kb; fw = fb; } else { wbl = ka; fw = fa; }
  } else {
    // ultra-rare: full exact scan of this half (LDS-local)
    float bb = -__builtin_inff(); int wbb = 0;
    for (int kl = 0; kl < HALF; kl++) {
      float ph;
      EXACT_PHI(ph, kl)
      if (ph > bb) { bb = ph; wbb = kl; }
    }
    wbl = wbb; fw = bb;
  }

  ws[(h << 18) + gp] = make_uint2(__float_as_uint(fw), (uint32_t)(wbl + h * HALF));
}

__global__ __launch_bounds__(256)
void mcq_combine(const uint2* __restrict__ ws, float* __restrict__ sample,
                 float* __restrict__ code) {
  __shared__ int s_wb[256];
  const int t = threadIdx.x;
  const int b = blockIdx.x;          // 1024 blocks x 256 pixels
  const int gp = (b << 8) + t;

  uint2 a = ws[gp];
  uint2 c = ws[P_TOT + gp];
  float fa = __uint_as_float(a.x);
  float fc = __uint_as_float(c.x);
  // exact compare; tie -> half 0 (smaller k, first occurrence)
  int win = (fc > fa) ? (int)c.y : (int)a.y;

  code[gp] = (float)win;
  s_wb[t] = win;
  __syncthreads();

  const int lane = t & 63, wv = t >> 6;
  const int pbase = b << 8;
  const int k0 = lane << 2;
  for (int r = wv * 64; r < (wv + 1) * 64; r++) {
    const int w = s_wb[r];
    float4 v;
    v.x = (w == k0 + 0) ? 1.0f : 0.0f;
    v.y = (w == k0 + 1) ? 1.0f : 0.0f;
    v.z = (w == k0 + 2) ? 1.0f : 0.0f;
    v.w = (w == k0 + 3) ? 1.0f : 0.0f;
    ((float4*)(sample + (((size_t)(pbase + r)) << 8)))[lane] = v;
  }
}

extern "C" void kernel_launch(void* const* d_in, const int* in_sizes, int n_in,
                              void* d_out, int out_size, void* d_ws, size_t ws_size,
                              hipStream_t stream) {
  const float* x  = (const float*)d_in[0];
  const float* cb = (const float*)d_in[1];

  float* out_f  = (float*)d_out;
  float* sample = out_f;                       // 67108864
  float* code   = out_f + 67108864;            // 262144 (as float)
  float* logit  = out_f + 67108864 + 262144;   // 67108864
  uint2* ws     = (uint2*)d_ws;                // 2 * 262144 * 8B = 4 MB

  mcq_main<<<2048, 256, 0, stream>>>(x, cb, logit, ws);
  mcq_combine<<<1024, 256, 0, stream>>>(ws, sample, code);
}